// Round 1
// baseline (305.473 us; speedup 1.0000x reference)
//
#include <hip/hip_runtime.h>

#define NTOK 4096
#define DDIM 1024
#define IDIM 704
#define NEXP 16
#define NSLOT 8192
#define MAXT 128
#define NPAD1 768    // IDIM padded to 128 multiple for gemm1 n-dim
#define RTRBLK 512   // router blocks (first in grid): 8 tokens each
#define TRBLK 2240   // transpose blocks: W1 768 + W3 768 + W2 704, each 64k x 256n

typedef __attribute__((ext_vector_type(8))) short bf16x8;
typedef __attribute__((ext_vector_type(4))) float f32x4;
typedef __attribute__((ext_vector_type(4))) unsigned short us4;
typedef __attribute__((ext_vector_type(8))) unsigned short us8;

__device__ __forceinline__ unsigned short f2bf(float f) {
  union { float f; unsigned int u; } v; v.f = f;
  unsigned int r = v.u + 0x7fffu + ((v.u >> 16) & 1u);
  return (unsigned short)(r >> 16);
}

__device__ __forceinline__ float bf2f(unsigned short b) {
  union { unsigned int u; float f; } v; v.u = ((unsigned int)b) << 16;
  return v.f;
}

__device__ __forceinline__ void gload_lds16(const void* g, void* l) {
  __builtin_amdgcn_global_load_lds((const __attribute__((address_space(1))) void*)g,
                                   (__attribute__((address_space(3))) void*)l, 16, 0, 0);
}

// ---------------- front: router (blocks 0..511, dispatched first so its L2-bound
// work overlaps the HBM-bound transpose) + weight transpose (blocks 512..2751,
// 64k x 256n per block => 256B of loads in flight per thread) ----------------
__global__ __launch_bounds__(256, 4)
void k_front(const float* __restrict__ x, const float* __restrict__ Wg,
             const float* __restrict__ W1, const float* __restrict__ W3,
             const float* __restrict__ W2, int* __restrict__ tok_e,
             float* __restrict__ tok_w, unsigned short* __restrict__ Xb,
             unsigned short* __restrict__ W1T, unsigned short* __restrict__ W3T,
             unsigned short* __restrict__ W2T) {
  int b = blockIdx.x;
  if (b >= RTRBLK) {
    __shared__ unsigned short lds[4][64 * 64];
    int tb = b - RTRBLK;
    const float* src; unsigned short* dst;
    int ksz, nsz, kx, np, e;
    if (tb < 1536) {              // W1: 0..767, W3: 768..1535 (16 kx x 3 np x 16 e)
      int which = tb >= 768 ? 1 : 0;
      int t2 = tb - which * 768;
      kx = t2 & 15; int rest = t2 >> 4; np = rest % 3; e = rest / 3;
      ksz = DDIM; nsz = IDIM;
      src = (which ? W3 : W1) + (size_t)e * DDIM * IDIM;
      dst = (which ? W3T : W1T) + (size_t)e * NPAD1 * DDIM;
    } else {                      // W2: 11 kx x 4 np x 16 e
      int t3 = tb - 1536;
      kx = t3 % 11; int rest = t3 / 11; np = rest & 3; e = rest >> 2;
      ksz = IDIM; nsz = DDIM;
      src = W2 + (size_t)e * IDIM * DDIM;
      dst = W2T + (size_t)e * DDIM * IDIM;
    }
    int k0 = kx * 64, n0 = np * 256;
    int t = threadIdx.x;
    int kr4 = (t >> 4) * 4, nc4 = (t & 15) * 4;
    f32x4 v[4][4];                // [n-subtile][k-row]
    bool val[4];
#pragma unroll
    for (int s = 0; s < 4; ++s) {
      val[s] = (n0 + s * 64 + 64) <= nsz;   // only pad-subtile of last W1/W3 np is invalid
      if (val[s]) {
#pragma unroll
        for (int j = 0; j < 4; ++j)
          v[s][j] = *(const f32x4*)(src + (size_t)(k0 + kr4 + j) * nsz + n0 + s * 64 + nc4);
      }
    }
    int c8 = kr4 >> 3, half = (kr4 >> 2) & 1;
#pragma unroll
    for (int s = 0; s < 4; ++s) {
      if (val[s]) {
#pragma unroll
        for (int i = 0; i < 4; ++i) {
          int row = nc4 + i;
          int addr = row * 64 + ((c8 ^ ((row >> 2) & 7)) << 3) + half * 4;
          us4 o;
#pragma unroll
          for (int j = 0; j < 4; ++j) o[j] = f2bf(v[s][j][i]);
          *(us4*)(lds[s] + addr) = o;
        }
      }
    }
    __syncthreads();
    int nr = t >> 3, kc8 = t & 7;
#pragma unroll
    for (int s = 0; s < 4; ++s) {
#pragma unroll
      for (int q = 0; q < 2; ++q) {
        int row = nr + q * 32;
        us8 o = val[s] ? *(const us8*)(lds[s] + row * 64 + ((kc8 ^ ((row >> 2) & 7)) << 3))
                       : (us8)(unsigned short)0;
        *(us8*)(dst + (size_t)(n0 + s * 64 + row) * ksz + k0 + kc8 * 8) = o;
      }
    }
    return;
  }
  // ---- router: 4 waves x 2 tokens/wave (Wg registers reused across both tokens) ----
  int lane = threadIdx.x & 63;
  int wv = threadIdx.x >> 6;
  int tk0 = b * 8 + wv * 2;
  f32x4 xv[2][4];
#pragma unroll
  for (int tok = 0; tok < 2; ++tok) {
    const f32x4* xr = (const f32x4*)(x + (size_t)(tk0 + tok) * DDIM);
    us4* xbr = (us4*)(Xb + (size_t)(tk0 + tok) * DDIM);
#pragma unroll
    for (int c = 0; c < 4; ++c) {
      xv[tok][c] = xr[c * 64 + lane];
      us4 o;
#pragma unroll
      for (int j = 0; j < 4; ++j) o[j] = f2bf(xv[tok][c][j]);
      xbr[c * 64 + lane] = o;
    }
  }
  float p[2][NEXP];
#pragma unroll
  for (int e = 0; e < NEXP; ++e) {
    const f32x4* wr = (const f32x4*)(Wg + (size_t)e * DDIM);
    float s0 = 0.f, s1 = 0.f;
#pragma unroll
    for (int c = 0; c < 4; ++c) {
      f32x4 w4 = wr[c * 64 + lane];
      s0 += xv[0][c][0]*w4[0] + xv[0][c][1]*w4[1] + xv[0][c][2]*w4[2] + xv[0][c][3]*w4[3];
      s1 += xv[1][c][0]*w4[0] + xv[1][c][1]*w4[1] + xv[1][c][2]*w4[2] + xv[1][c][3]*w4[3];
    }
    p[0][e] = s0; p[1][e] = s1;
  }
#pragma unroll
  for (int off = 32; off >= 1; off >>= 1)
#pragma unroll
    for (int e = 0; e < NEXP; ++e) {
      p[0][e] += __shfl_xor(p[0][e], off);
      p[1][e] += __shfl_xor(p[1][e], off);
    }
#pragma unroll
  for (int tok = 0; tok < 2; ++tok) {
    int i0 = 0; float b0 = p[tok][0];
#pragma unroll
    for (int e = 1; e < NEXP; ++e) if (p[tok][e] > b0) { b0 = p[tok][e]; i0 = e; }
    int i1 = -1; float b1 = -3.4e38f;
#pragma unroll
    for (int e = 0; e < NEXP; ++e) if (e != i0 && p[tok][e] > b1) { b1 = p[tok][e]; i1 = e; }
    if (lane == 0) {
      int tk = tk0 + tok;
      float w0 = 1.f / (1.f + __expf(b1 - b0));   // renormalized top-2 softmax weight
      tok_e[2*tk] = i0; tok_e[2*tk+1] = i1;
      tok_w[2*tk] = w0; tok_w[2*tk+1] = 1.f - w0;
    }
  }
}

// ---------------- count+scan+scatter: 16 blocks, no atomics ----------------
// Pass 1 now builds all 16 expert masks from 4 bit-ballots (instead of 16
// ballots), with the tok_e load software-pipelined one segment ahead.
__global__ void k_scan_scatter(const int* __restrict__ tok_e, const float* __restrict__ tok_w,
                               int* __restrict__ counts, int* __restrict__ offsets,
                               int* __restrict__ ntiles, int* __restrict__ tile_e,
                               int* __restrict__ tile_m0, int* __restrict__ token_map,
                               float* __restrict__ gate_w, int* __restrict__ slot_of) {
  int eb = blockIdx.x;
  int t = threadIdx.x, lane = t & 63, wv = t >> 6;
  __shared__ unsigned long long masks[4][32];   // expert-eb ballot per [wave][seg]
  __shared__ int wcnt[4][NEXP];                 // per-wave per-expert counts
  __shared__ int counts_s[NEXP];
  int ce[NEXP];
#pragma unroll
  for (int e = 0; e < NEXP; ++e) ce[e] = 0;
  int base = wv * 2048 + lane;
  int te = tok_e[base];
#pragma unroll 1
  for (int s = 0; s < 32; ++s) {
    int ten = (s < 31) ? tok_e[base + (s + 1) * 64] : 0;
    unsigned long long B0 = __ballot(te & 1);
    unsigned long long B1 = __ballot(te & 2);
    unsigned long long B2 = __ballot(te & 4);
    unsigned long long B3 = __ballot(te & 8);
#pragma unroll
    for (int e = 0; e < NEXP; ++e) {
      unsigned long long m = ((e & 1) ? B0 : ~B0) & ((e & 2) ? B1 : ~B1) &
                             ((e & 4) ? B2 : ~B2) & ((e & 8) ? B3 : ~B3);
      ce[e] += (int)__popcll(m);
      if (e == eb && lane == 0) masks[wv][s] = m;
    }
    te = ten;
  }
  if (lane == 0) {
#pragma unroll
    for (int e = 0; e < NEXP; ++e) wcnt[wv][e] = ce[e];
  }
  __syncthreads();
  if (t < NEXP) {
    int s = wcnt[0][t] + wcnt[1][t] + wcnt[2][t] + wcnt[3][t];
    counts_s[t] = s;
    if (eb == 0) counts[t] = s;
  }
  __syncthreads();
  if (eb == 0 && t == 0) {
    int acc = 0, nt = 0;
    for (int e = 0; e < NEXP; ++e) {
      offsets[e] = acc;
      int cc = counts_s[e];
      for (int m0 = 0; m0 < cc; m0 += 128) { tile_e[nt] = e; tile_m0[nt] = m0; ++nt; }
      acc += cc;
    }
    offsets[NEXP] = acc;
    *ntiles = nt;
  }
  int run = 0;
  for (int e = 0; e < eb; ++e) run += counts_s[e];            // expert base
  for (int w = 0; w < wv; ++w) run += wcnt[w][eb];            // wave base
  unsigned long long below = (lane == 63) ? 0x7fffffffffffffffull : ((1ull << lane) - 1ull);
#pragma unroll 1
  for (int s = 0; s < 32; ++s) {
    unsigned long long m = masks[wv][s];
    if ((m >> lane) & 1ull) {
      int i = wv * 2048 + s * 64 + lane;
      int slot = run + (int)__popcll(m & below);
      token_map[slot] = i >> 1;
      gate_w[slot] = tok_w[i];
      slot_of[i] = slot;
    }
    run += (int)__popcll(m);
  }
}

// ---------------- GEMM1: 128x128, double-buffered LDS, XCD-swizzled ----------------
__global__ __launch_bounds__(256, 2)
void k_gemm1(const unsigned short* __restrict__ Xb, const unsigned short* __restrict__ W1T,
             const unsigned short* __restrict__ W3T, const int* __restrict__ token_map,
             const float* __restrict__ gate_w, const int* __restrict__ ntiles,
             const int* __restrict__ tile_e, const int* __restrict__ tile_m0,
             const int* __restrict__ offsets, const int* __restrict__ counts,
             unsigned short* __restrict__ H) {
  int idx = blockIdx.x;
  int xcd = idx & 7, r = idx >> 3;
  int g = (r >> 2) * 8 + xcd;       // 0..119
  int mm = r & 3;
  int ty = (g / 6) * 4 + mm;        // 0..79
  if (ty >= *ntiles) return;
  int n0 = (g % 6) * 128;
  int e = tile_e[ty], m0 = tile_m0[ty];
  int base_slot = offsets[e] + m0;
  int cnt = counts[e] - m0; if (cnt > 128) cnt = 128;

  __shared__ unsigned short As[2][128 * 32];
  __shared__ unsigned short B1s[2][128 * 32];
  __shared__ unsigned short B3s[2][128 * 32];

  int t = threadIdx.x;
  int row = t >> 2, kc = (t & 3) * 8;
  int r0i = base_slot + row;      if (r0i > NSLOT - 1) r0i = NSLOT - 1;
  int r1i = base_slot + 64 + row; if (r1i > NSLOT - 1) r1i = NSLOT - 1;
  const unsigned short* ag0 = Xb + (size_t)token_map[r0i] * DDIM + kc;
  const unsigned short* ag1 = Xb + (size_t)token_map[r1i] * DDIM + kc;
  const unsigned short* b1g0 = W1T + ((size_t)e * NPAD1 + n0 + row) * DDIM + kc;
  const unsigned short* b1g1 = b1g0 + (size_t)64 * DDIM;
  const unsigned short* b3g0 = W3T + ((size_t)e * NPAD1 + n0 + row) * DDIM + kc;
  const unsigned short* b3g1 = b3g0 + (size_t)64 * DDIM;
  int d0 = t * 8, d1 = 2048 + t * 8;

  int lane = t & 63, wv = t >> 6;
  int wm = (wv >> 1) * 64, wn = (wv & 1) * 64;
  int lm = lane & 15, kg = lane >> 4;
  int ao[4], bo[4];
#pragma unroll
  for (int i = 0; i < 4; ++i) {
    ao[i] = (wm + i * 16 + lm) * 32 + kg * 8;
    bo[i] = (wn + i * 16 + lm) * 32 + kg * 8;
  }

  f32x4 acc1[4][4], acc3[4][4];
#pragma unroll
  for (int i = 0; i < 4; ++i)
#pragma unroll
    for (int j = 0; j < 4; ++j) { acc1[i][j] = 0.f; acc3[i][j] = 0.f; }

  gload_lds16(ag0, As[0] + d0);
  gload_lds16(ag1, As[0] + d1);
  gload_lds16(b1g0, B1s[0] + d0);
  gload_lds16(b1g1, B1s[0] + d1);
  gload_lds16(b3g0, B3s[0] + d0);
  gload_lds16(b3g1, B3s[0] + d1);

  for (int k0 = 0; k0 < DDIM; k0 += 32) {
    int cur = (k0 >> 5) & 1;
    __syncthreads();
    if (k0 + 32 < DDIM) {
      int nx = cur ^ 1, kn = k0 + 32;
      gload_lds16(ag0 + kn, As[nx] + d0);
      gload_lds16(ag1 + kn, As[nx] + d1);
      gload_lds16(b1g0 + kn, B1s[nx] + d0);
      gload_lds16(b1g1 + kn, B1s[nx] + d1);
      gload_lds16(b3g0 + kn, B3s[nx] + d0);
      gload_lds16(b3g1 + kn, B3s[nx] + d1);
    }
    bf16x8 av[4], b1v[4], b3v[4];
#pragma unroll
    for (int i = 0; i < 4; ++i) {
      av[i]  = *(const bf16x8*)(As[cur] + ao[i]);
      b1v[i] = *(const bf16x8*)(B1s[cur] + bo[i]);
      b3v[i] = *(const bf16x8*)(B3s[cur] + bo[i]);
    }
#pragma unroll
    for (int mi = 0; mi < 4; ++mi)
#pragma unroll
      for (int ni = 0; ni < 4; ++ni) {
        acc1[mi][ni] = __builtin_amdgcn_mfma_f32_16x16x32_bf16(av[mi], b1v[ni], acc1[mi][ni], 0, 0, 0);
        acc3[mi][ni] = __builtin_amdgcn_mfma_f32_16x16x32_bf16(av[mi], b3v[ni], acc3[mi][ni], 0, 0, 0);
      }
  }

#pragma unroll
  for (int mi = 0; mi < 4; ++mi)
#pragma unroll
    for (int rr = 0; rr < 4; ++rr) {
      int orow = wm + mi * 16 + kg * 4 + rr;
      if (orow < cnt) {
        int slot = base_slot + orow;
        float gw = gate_w[slot];
        unsigned short* hrow = H + (size_t)slot * IDIM;
#pragma unroll
        for (int ni = 0; ni < 4; ++ni) {
          int nn = n0 + wn + ni * 16 + lm;
          if (nn < IDIM) {
            float v1 = acc1[mi][ni][rr];
            float v3 = acc3[mi][ni][rr];
            float hh = v1 / (1.f + __expf(-v1)) * v3 * gw;
            hrow[nn] = f2bf(hh);
          }
        }
      }
    }
}

// ---------------- GEMM2: 128x128, double-buffered LDS, bf16 output ----------------
__global__ __launch_bounds__(256, 3)
void k_gemm2(const unsigned short* __restrict__ H, const unsigned short* __restrict__ W2T,
             const int* __restrict__ ntiles, const int* __restrict__ tile_e,
             const int* __restrict__ tile_m0, const int* __restrict__ offsets,
             const int* __restrict__ counts, unsigned short* __restrict__ O2) {
  int idx = blockIdx.x;
  int xcd = idx & 7, r = idx >> 3;
  int g = (r >> 2) * 8 + xcd;       // 0..159
  int mm = r & 3;
  int ty = (g >> 3) * 4 + mm;       // 0..79
  if (ty >= *ntiles) return;
  int n0 = (g & 7) * 128;
  int e = tile_e[ty], m0 = tile_m0[ty];
  int base_slot = offsets[e] + m0;
  int cnt = counts[e] - m0; if (cnt > 128) cnt = 128;

  __shared__ unsigned short As[2][128 * 32];
  __shared__ unsigned short Bs[2][128 * 32];

  int t = threadIdx.x;
  int row = t >> 2, kc = (t & 3) * 8;
  int r0i = base_slot + row;      if (r0i > NSLOT - 1) r0i = NSLOT - 1;
  int r1i = base_slot + 64 + row; if (r1i > NSLOT - 1) r1i = NSLOT - 1;
  const unsigned short* ag0 = H + (size_t)r0i * IDIM + kc;
  const unsigned short* ag1 = H + (size_t)r1i * IDIM + kc;
  const unsigned short* bg0 = W2T + ((size_t)e * DDIM + n0 + row) * IDIM + kc;
  const unsigned short* bg1 = bg0 + (size_t)64 * IDIM;
  int d0 = t * 8, d1 = 2048 + t * 8;

  int lane = t & 63, wv = t >> 6;
  int wm = (wv >> 1) * 64, wn = (wv & 1) * 64;
  int lm = lane & 15, kg = lane >> 4;
  int ao[4], bo[4];
#pragma unroll
  for (int i = 0; i < 4; ++i) {
    ao[i] = (wm + i * 16 + lm) * 32 + kg * 8;
    bo[i] = (wn + i * 16 + lm) * 32 + kg * 8;
  }

  f32x4 acc[4][4];
#pragma unroll
  for (int i = 0; i < 4; ++i)
#pragma unroll
    for (int j = 0; j < 4; ++j) acc[i][j] = 0.f;

  gload_lds16(ag0, As[0] + d0);
  gload_lds16(ag1, As[0] + d1);
  gload_lds16(bg0, Bs[0] + d0);
  gload_lds16(bg1, Bs[0] + d1);

  for (int k0 = 0; k0 < IDIM; k0 += 32) {
    int cur = (k0 >> 5) & 1;
    __syncthreads();
    if (k0 + 32 < IDIM) {
      int nx = cur ^ 1, kn = k0 + 32;
      gload_lds16(ag0 + kn, As[nx] + d0);
      gload_lds16(ag1 + kn, As[nx] + d1);
      gload_lds16(bg0 + kn, Bs[nx] + d0);
      gload_lds16(bg1 + kn, Bs[nx] + d1);
    }
    bf16x8 av[4], bv[4];
#pragma unroll
    for (int i = 0; i < 4; ++i) {
      av[i] = *(const bf16x8*)(As[cur] + ao[i]);
      bv[i] = *(const bf16x8*)(Bs[cur] + bo[i]);
    }
#pragma unroll
    for (int mi = 0; mi < 4; ++mi)
#pragma unroll
      for (int ni = 0; ni < 4; ++ni)
        acc[mi][ni] = __builtin_amdgcn_mfma_f32_16x16x32_bf16(av[mi], bv[ni], acc[mi][ni], 0, 0, 0);
  }

#pragma unroll
  for (int mi = 0; mi < 4; ++mi)
#pragma unroll
    for (int rr = 0; rr < 4; ++rr) {
      int orow = wm + mi * 16 + kg * 4 + rr;
      if (orow < cnt) {
        unsigned short* op = O2 + (size_t)(base_slot + orow) * DDIM + n0;
#pragma unroll
        for (int ni = 0; ni < 4; ++ni)
          op[wn + ni * 16 + lm] = f2bf(acc[mi][ni][rr]);
      }
    }
}

// ---------------- combine: out[t] = O2[slot0] + O2[slot1] (bf16 in, fp32 out) ----------------
__global__ void k_combine(const unsigned short* __restrict__ O2, const int* __restrict__ slot_of,
                          float* __restrict__ out) {
  int tk = blockIdx.x, tt = threadIdx.x;
  int s0 = slot_of[2 * tk], s1 = slot_of[2 * tk + 1];
  us4 a = ((const us4*)(O2 + (size_t)s0 * DDIM))[tt];
  us4 b = ((const us4*)(O2 + (size_t)s1 * DDIM))[tt];
  f32x4 o;
#pragma unroll
  for (int j = 0; j < 4; ++j) o[j] = bf2f(a[j]) + bf2f(b[j]);
  ((f32x4*)(out + (size_t)tk * DDIM))[tt] = o;
}

extern "C" void kernel_launch(void* const* d_in, const int* in_sizes, int n_in,
                              void* d_out, int out_size, void* d_ws, size_t ws_size,
                              hipStream_t stream) {
  const float* x  = (const float*)d_in[0];
  const float* Wg = (const float*)d_in[1];
  const float* W1 = (const float*)d_in[2];
  const float* W2 = (const float*)d_in[3];   // dict order: x, Wg, W1, W2, W3
  const float* W3 = (const float*)d_in[4];
  float* out = (float*)d_out;

  char* ws = (char*)d_ws;
  size_t off = 0;
  unsigned short* Xb = (unsigned short*)(ws + off); off += (size_t)NTOK * DDIM * 2;
  unsigned short* H  = (unsigned short*)(ws + off); off += (size_t)NSLOT * IDIM * 2;
  unsigned short* O2 = (unsigned short*)(ws + off); off += (size_t)NSLOT * DDIM * 2;
  unsigned short* W1T = (unsigned short*)(ws + off); off += (size_t)NEXP * NPAD1 * DDIM * 2;
  unsigned short* W3T = (unsigned short*)(ws + off); off += (size_t)NEXP * NPAD1 * DDIM * 2;
  unsigned short* W2T = (unsigned short*)(ws + off); off += (size_t)NEXP * DDIM * IDIM * 2;
  int* counts  = (int*)(ws + off); off += 64;
  int* offsets = (int*)(ws + off); off += 128;
  int* ntiles  = (int*)(ws + off); off += 64;
  int* tile_e  = (int*)(ws + off); off += MAXT * 4;
  int* tile_m0 = (int*)(ws + off); off += MAXT * 4;
  int* tok_e   = (int*)(ws + off); off += NSLOT * 4;
  float* tok_w = (float*)(ws + off); off += NSLOT * 4;
  int* token_map = (int*)(ws + off); off += NSLOT * 4;
  float* gate_w  = (float*)(ws + off); off += NSLOT * 4;
  int* slot_of   = (int*)(ws + off); off += NSLOT * 4;

  k_front<<<RTRBLK + TRBLK, 256, 0, stream>>>(x, Wg, W1, W3, W2, tok_e, tok_w, Xb,
                                              W1T, W3T, W2T);
  k_scan_scatter<<<NEXP, 256, 0, stream>>>(tok_e, tok_w, counts, offsets, ntiles,
                                           tile_e, tile_m0, token_map, gate_w, slot_of);
  k_gemm1<<<480, 256, 0, stream>>>(Xb, W1T, W3T, token_map, gate_w, ntiles, tile_e,
                                   tile_m0, offsets, counts, H);
  k_gemm2<<<640, 256, 0, stream>>>(H, W2T, ntiles, tile_e, tile_m0, offsets, counts, O2);
  k_combine<<<4096, 256, 0, stream>>>(O2, slot_of, out);
}

// Round 3
// 303.767 us; speedup vs baseline: 1.0056x; 1.0056x over previous
//
#include <hip/hip_runtime.h>

#define NTOK 4096
#define DDIM 1024
#define IDIM 704
#define NEXP 16
#define NSLOT 8192
#define MAXT 128
#define NPAD1 768    // IDIM padded to 128 multiple for gemm1 n-dim
#define RTRBLK 512   // router blocks (first in grid): 8 tokens each
#define TRBLK 1152   // transpose blocks: W1 384 + W3 384 + W2 384, each 256k x 128n

typedef __attribute__((ext_vector_type(8))) short bf16x8;
typedef __attribute__((ext_vector_type(4))) float f32x4;
typedef __attribute__((ext_vector_type(4))) unsigned short us4;
typedef __attribute__((ext_vector_type(8))) unsigned short us8;

__device__ __forceinline__ unsigned short f2bf(float f) {
  union { float f; unsigned int u; } v; v.f = f;
  unsigned int r = v.u + 0x7fffu + ((v.u >> 16) & 1u);
  return (unsigned short)(r >> 16);
}

__device__ __forceinline__ float bf2f(unsigned short b) {
  union { unsigned int u; float f; } v; v.u = ((unsigned int)b) << 16;
  return v.f;
}

__device__ __forceinline__ void gload_lds16(const void* g, void* l) {
  __builtin_amdgcn_global_load_lds((const __attribute__((address_space(1))) void*)g,
                                   (__attribute__((address_space(3))) void*)l, 16, 0, 0);
}

// ---------------- front: router (blocks 0..511) + weight transpose (512..1663) ----
// Transpose tile = 256k x 128n. Reads: 512B contiguous per 32-lane group (one
// k-row segment of 128 f32). Writes: 512B contiguous per 32-lane group (one
// n-row segment of 256 bf16). LDS: [128 rows][512B], 16B-chunk rotate swizzle
// phys = (chunk + row/4) & 31.
__global__ __launch_bounds__(256, 2)
void k_front(const float* __restrict__ x, const float* __restrict__ Wg,
             const float* __restrict__ W1, const float* __restrict__ W3,
             const float* __restrict__ W2, int* __restrict__ tok_e,
             float* __restrict__ tok_w, unsigned short* __restrict__ Xb,
             unsigned short* __restrict__ W1T, unsigned short* __restrict__ W3T,
             unsigned short* __restrict__ W2T) {
  int b = blockIdx.x;
  if (b >= RTRBLK) {
    __shared__ char ldsb[128 * 512];      // 64 KiB
    int tb = b - RTRBLK;
    const float* src; unsigned short* dst;
    int KS, NS, k0, n0;
    if (tb < 768) {                       // W1: 0..383, W3: 384..767
      int which = tb >= 384 ? 1 : 0;
      int t2 = tb - which * 384;
      int e = t2 / 24, rem = t2 % 24;
      int kb = rem / 6, nb = rem % 6;     // 4 k-blocks x 6 n-blocks
      KS = DDIM; NS = IDIM;
      k0 = kb * 256; n0 = nb * 128;
      src = (which ? W3 : W1) + (size_t)e * DDIM * IDIM;
      dst = (which ? W3T : W1T) + (size_t)e * NPAD1 * DDIM;
    } else {                              // W2: 3 k-blocks x 8 n-blocks
      int t2 = tb - 768;
      int e = t2 / 24, rem = t2 % 24;
      int kb = rem / 8, nb = rem % 8;
      KS = IDIM; NS = DDIM;
      k0 = kb * 256; n0 = nb * 128;
      src = W2 + (size_t)e * IDIM * DDIM;
      dst = W2T + (size_t)e * DDIM * IDIM;
    }
    int t = threadIdx.x;
    int l = t & 31;                       // lane-in-group: n-quad index
    int g8 = t >> 5;                      // 0..7: k sub-row group
    int n4 = l * 4;                       // local n of this thread's 4 cols
    int nn = n0 + n4;
    bool nok = (nn + 4) <= NS;
    // phase 1: load 4k x 4n micro-tiles, register-transpose, swizzled LDS write
#pragma unroll
    for (int h = 0; h < 2; ++h) {
      f32x4 v[4][4];
#pragma unroll
      for (int i = 0; i < 4; ++i) {
        int kl0 = (h * 4 + i) * 32 + g8 * 4;
#pragma unroll
        for (int j = 0; j < 4; ++j) {
          int kk = k0 + kl0 + j;
          bool ok = nok && (kk < KS);
          v[i][j] = ok ? *(const f32x4*)(src + (size_t)kk * NS + nn) : (f32x4)0.f;
        }
      }
#pragma unroll
      for (int i = 0; i < 4; ++i) {
        int kl0 = (h * 4 + i) * 32 + g8 * 4;
        int chunk0 = kl0 >> 3;            // 16B chunk index within row
        int off8 = (kl0 * 2) & 15;        // 0 or 8
        int phys = (chunk0 + l) & 31;     // row>>2 == l for all 4 c's
#pragma unroll
        for (int c = 0; c < 4; ++c) {
          int row = n4 + c;
          us4 o = { f2bf(v[i][0][c]), f2bf(v[i][1][c]), f2bf(v[i][2][c]), f2bf(v[i][3][c]) };
          *(us4*)(ldsb + row * 512 + phys * 16 + off8) = o;
        }
      }
    }
    __syncthreads();
    // phase 2: write n-rows, 512B contiguous per 32-lane group
    int cl = t & 31;                      // k-chunk (16B = 8 bf16)
    int rg = t >> 5;                      // 0..7
    int kk = k0 + cl * 8;
    bool kok = kk < KS;
#pragma unroll
    for (int r = 0; r < 16; ++r) {
      int row = r * 8 + rg;               // local n row 0..127
      int phys = (cl + (row >> 2)) & 31;
      us8 o = *(const us8*)(ldsb + row * 512 + phys * 16);
      if (kok)
        *(us8*)(dst + (size_t)(n0 + row) * KS + kk) = o;
    }
    return;
  }
  // ---- router: 4 waves x 2 tokens/wave (Wg registers reused across both tokens) ----
  int lane = threadIdx.x & 63;
  int wv = threadIdx.x >> 6;
  int tk0 = b * 8 + wv * 2;
  f32x4 xv[2][4];
#pragma unroll
  for (int tok = 0; tok < 2; ++tok) {
    const f32x4* xr = (const f32x4*)(x + (size_t)(tk0 + tok) * DDIM);
    us4* xbr = (us4*)(Xb + (size_t)(tk0 + tok) * DDIM);
#pragma unroll
    for (int c = 0; c < 4; ++c) {
      xv[tok][c] = xr[c * 64 + lane];
      us4 o;
#pragma unroll
      for (int j = 0; j < 4; ++j) o[j] = f2bf(xv[tok][c][j]);
      xbr[c * 64 + lane] = o;
    }
  }
  float p[2][NEXP];
#pragma unroll
  for (int e = 0; e < NEXP; ++e) {
    const f32x4* wr = (const f32x4*)(Wg + (size_t)e * DDIM);
    float s0 = 0.f, s1 = 0.f;
#pragma unroll
    for (int c = 0; c < 4; ++c) {
      f32x4 w4 = wr[c * 64 + lane];
      s0 += xv[0][c][0]*w4[0] + xv[0][c][1]*w4[1] + xv[0][c][2]*w4[2] + xv[0][c][3]*w4[3];
      s1 += xv[1][c][0]*w4[0] + xv[1][c][1]*w4[1] + xv[1][c][2]*w4[2] + xv[1][c][3]*w4[3];
    }
    p[0][e] = s0; p[1][e] = s1;
  }
#pragma unroll
  for (int off = 32; off >= 1; off >>= 1)
#pragma unroll
    for (int e = 0; e < NEXP; ++e) {
      p[0][e] += __shfl_xor(p[0][e], off);
      p[1][e] += __shfl_xor(p[1][e], off);
    }
#pragma unroll
  for (int tok = 0; tok < 2; ++tok) {
    int i0 = 0; float b0 = p[tok][0];
#pragma unroll
    for (int e = 1; e < NEXP; ++e) if (p[tok][e] > b0) { b0 = p[tok][e]; i0 = e; }
    int i1 = -1; float b1 = -3.4e38f;
#pragma unroll
    for (int e = 0; e < NEXP; ++e) if (e != i0 && p[tok][e] > b1) { b1 = p[tok][e]; i1 = e; }
    if (lane == 0) {
      int tk = tk0 + tok;
      float w0 = 1.f / (1.f + __expf(b1 - b0));   // renormalized top-2 softmax weight
      tok_e[2*tk] = i0; tok_e[2*tk+1] = i1;
      tok_w[2*tk] = w0; tok_w[2*tk+1] = 1.f - w0;
    }
  }
}

// ---------------- count+scan+scatter: 16 blocks, no atomics ----------------
__global__ void k_scan_scatter(const int* __restrict__ tok_e, const float* __restrict__ tok_w,
                               int* __restrict__ counts, int* __restrict__ offsets,
                               int* __restrict__ ntiles, int* __restrict__ tile_e,
                               int* __restrict__ tile_m0, int* __restrict__ token_map,
                               float* __restrict__ gate_w, int* __restrict__ slot_of) {
  int eb = blockIdx.x;
  int t = threadIdx.x, lane = t & 63, wv = t >> 6;
  __shared__ unsigned long long masks[4][32];   // expert-eb ballot per [wave][seg]
  __shared__ int wcnt[4][NEXP];                 // per-wave per-expert counts
  __shared__ int counts_s[NEXP];
  int ce[NEXP];
#pragma unroll
  for (int e = 0; e < NEXP; ++e) ce[e] = 0;
  int base = wv * 2048 + lane;
  int te = tok_e[base];
#pragma unroll 1
  for (int s = 0; s < 32; ++s) {
    int ten = (s < 31) ? tok_e[base + (s + 1) * 64] : 0;
    unsigned long long B0 = __ballot(te & 1);
    unsigned long long B1 = __ballot(te & 2);
    unsigned long long B2 = __ballot(te & 4);
    unsigned long long B3 = __ballot(te & 8);
#pragma unroll
    for (int e = 0; e < NEXP; ++e) {
      unsigned long long m = ((e & 1) ? B0 : ~B0) & ((e & 2) ? B1 : ~B1) &
                             ((e & 4) ? B2 : ~B2) & ((e & 8) ? B3 : ~B3);
      ce[e] += (int)__popcll(m);
      if (e == eb && lane == 0) masks[wv][s] = m;
    }
    te = ten;
  }
  if (lane == 0) {
#pragma unroll
    for (int e = 0; e < NEXP; ++e) wcnt[wv][e] = ce[e];
  }
  __syncthreads();
  if (t < NEXP) {
    int s = wcnt[0][t] + wcnt[1][t] + wcnt[2][t] + wcnt[3][t];
    counts_s[t] = s;
    if (eb == 0) counts[t] = s;
  }
  __syncthreads();
  if (eb == 0 && t == 0) {
    int acc = 0, nt = 0;
    for (int e = 0; e < NEXP; ++e) {
      offsets[e] = acc;
      int cc = counts_s[e];
      for (int m0 = 0; m0 < cc; m0 += 128) { tile_e[nt] = e; tile_m0[nt] = m0; ++nt; }
      acc += cc;
    }
    offsets[NEXP] = acc;
    *ntiles = nt;
  }
  int run = 0;
  for (int e = 0; e < eb; ++e) run += counts_s[e];            // expert base
  for (int w = 0; w < wv; ++w) run += wcnt[w][eb];            // wave base
  unsigned long long below = (lane == 63) ? 0x7fffffffffffffffull : ((1ull << lane) - 1ull);
#pragma unroll 1
  for (int s = 0; s < 32; ++s) {
    unsigned long long m = masks[wv][s];
    if ((m >> lane) & 1ull) {
      int i = wv * 2048 + s * 64 + lane;
      int slot = run + (int)__popcll(m & below);
      token_map[slot] = i >> 1;
      gate_w[slot] = tok_w[i];
      slot_of[i] = slot;
    }
    run += (int)__popcll(m);
  }
}

// ---------------- GEMM1: 128x128, double-buffered LDS, XCD-swizzled ----------------
__global__ __launch_bounds__(256, 2)
void k_gemm1(const unsigned short* __restrict__ Xb, const unsigned short* __restrict__ W1T,
             const unsigned short* __restrict__ W3T, const int* __restrict__ token_map,
             const float* __restrict__ gate_w, const int* __restrict__ ntiles,
             const int* __restrict__ tile_e, const int* __restrict__ tile_m0,
             const int* __restrict__ offsets, const int* __restrict__ counts,
             unsigned short* __restrict__ H) {
  int idx = blockIdx.x;
  int xcd = idx & 7, r = idx >> 3;
  int g = (r >> 2) * 8 + xcd;       // 0..119
  int mm = r & 3;
  int ty = (g / 6) * 4 + mm;        // 0..79
  if (ty >= *ntiles) return;
  int n0 = (g % 6) * 128;
  int e = tile_e[ty], m0 = tile_m0[ty];
  int base_slot = offsets[e] + m0;
  int cnt = counts[e] - m0; if (cnt > 128) cnt = 128;

  __shared__ unsigned short As[2][128 * 32];
  __shared__ unsigned short B1s[2][128 * 32];
  __shared__ unsigned short B3s[2][128 * 32];

  int t = threadIdx.x;
  int row = t >> 2, kc = (t & 3) * 8;
  int r0i = base_slot + row;      if (r0i > NSLOT - 1) r0i = NSLOT - 1;
  int r1i = base_slot + 64 + row; if (r1i > NSLOT - 1) r1i = NSLOT - 1;
  const unsigned short* ag0 = Xb + (size_t)token_map[r0i] * DDIM + kc;
  const unsigned short* ag1 = Xb + (size_t)token_map[r1i] * DDIM + kc;
  const unsigned short* b1g0 = W1T + ((size_t)e * NPAD1 + n0 + row) * DDIM + kc;
  const unsigned short* b1g1 = b1g0 + (size_t)64 * DDIM;
  const unsigned short* b3g0 = W3T + ((size_t)e * NPAD1 + n0 + row) * DDIM + kc;
  const unsigned short* b3g1 = b3g0 + (size_t)64 * DDIM;
  int d0 = t * 8, d1 = 2048 + t * 8;

  int lane = t & 63, wv = t >> 6;
  int wm = (wv >> 1) * 64, wn = (wv & 1) * 64;
  int lm = lane & 15, kg = lane >> 4;
  int ao[4], bo[4];
#pragma unroll
  for (int i = 0; i < 4; ++i) {
    ao[i] = (wm + i * 16 + lm) * 32 + kg * 8;
    bo[i] = (wn + i * 16 + lm) * 32 + kg * 8;
  }

  f32x4 acc1[4][4], acc3[4][4];
#pragma unroll
  for (int i = 0; i < 4; ++i)
#pragma unroll
    for (int j = 0; j < 4; ++j) { acc1[i][j] = 0.f; acc3[i][j] = 0.f; }

  gload_lds16(ag0, As[0] + d0);
  gload_lds16(ag1, As[0] + d1);
  gload_lds16(b1g0, B1s[0] + d0);
  gload_lds16(b1g1, B1s[0] + d1);
  gload_lds16(b3g0, B3s[0] + d0);
  gload_lds16(b3g1, B3s[0] + d1);

  for (int k0 = 0; k0 < DDIM; k0 += 32) {
    int cur = (k0 >> 5) & 1;
    __syncthreads();
    if (k0 + 32 < DDIM) {
      int nx = cur ^ 1, kn = k0 + 32;
      gload_lds16(ag0 + kn, As[nx] + d0);
      gload_lds16(ag1 + kn, As[nx] + d1);
      gload_lds16(b1g0 + kn, B1s[nx] + d0);
      gload_lds16(b1g1 + kn, B1s[nx] + d1);
      gload_lds16(b3g0 + kn, B3s[nx] + d0);
      gload_lds16(b3g1 + kn, B3s[nx] + d1);
    }
    bf16x8 av[4], b1v[4], b3v[4];
#pragma unroll
    for (int i = 0; i < 4; ++i) {
      av[i]  = *(const bf16x8*)(As[cur] + ao[i]);
      b1v[i] = *(const bf16x8*)(B1s[cur] + bo[i]);
      b3v[i] = *(const bf16x8*)(B3s[cur] + bo[i]);
    }
#pragma unroll
    for (int mi = 0; mi < 4; ++mi)
#pragma unroll
      for (int ni = 0; ni < 4; ++ni) {
        acc1[mi][ni] = __builtin_amdgcn_mfma_f32_16x16x32_bf16(av[mi], b1v[ni], acc1[mi][ni], 0, 0, 0);
        acc3[mi][ni] = __builtin_amdgcn_mfma_f32_16x16x32_bf16(av[mi], b3v[ni], acc3[mi][ni], 0, 0, 0);
      }
  }

#pragma unroll
  for (int mi = 0; mi < 4; ++mi)
#pragma unroll
    for (int rr = 0; rr < 4; ++rr) {
      int orow = wm + mi * 16 + kg * 4 + rr;
      if (orow < cnt) {
        int slot = base_slot + orow;
        float gw = gate_w[slot];
        unsigned short* hrow = H + (size_t)slot * IDIM;
#pragma unroll
        for (int ni = 0; ni < 4; ++ni) {
          int nn = n0 + wn + ni * 16 + lm;
          if (nn < IDIM) {
            float v1 = acc1[mi][ni][rr];
            float v3 = acc3[mi][ni][rr];
            float hh = v1 / (1.f + __expf(-v1)) * v3 * gw;
            hrow[nn] = f2bf(hh);
          }
        }
      }
    }
}

// ---------------- GEMM2: 128x128, double-buffered LDS, bf16 output ----------------
__global__ __launch_bounds__(256, 3)
void k_gemm2(const unsigned short* __restrict__ H, const unsigned short* __restrict__ W2T,
             const int* __restrict__ ntiles, const int* __restrict__ tile_e,
             const int* __restrict__ tile_m0, const int* __restrict__ offsets,
             const int* __restrict__ counts, unsigned short* __restrict__ O2) {
  int idx = blockIdx.x;
  int xcd = idx & 7, r = idx >> 3;
  int g = (r >> 2) * 8 + xcd;       // 0..159
  int mm = r & 3;
  int ty = (g >> 3) * 4 + mm;       // 0..79
  if (ty >= *ntiles) return;
  int n0 = (g & 7) * 128;
  int e = tile_e[ty], m0 = tile_m0[ty];
  int base_slot = offsets[e] + m0;
  int cnt = counts[e] - m0; if (cnt > 128) cnt = 128;

  __shared__ unsigned short As[2][128 * 32];
  __shared__ unsigned short Bs[2][128 * 32];

  int t = threadIdx.x;
  int row = t >> 2, kc = (t & 3) * 8;
  int r0i = base_slot + row;      if (r0i > NSLOT - 1) r0i = NSLOT - 1;
  int r1i = base_slot + 64 + row; if (r1i > NSLOT - 1) r1i = NSLOT - 1;
  const unsigned short* ag0 = H + (size_t)r0i * IDIM + kc;
  const unsigned short* ag1 = H + (size_t)r1i * IDIM + kc;
  const unsigned short* bg0 = W2T + ((size_t)e * DDIM + n0 + row) * IDIM + kc;
  const unsigned short* bg1 = bg0 + (size_t)64 * IDIM;
  int d0 = t * 8, d1 = 2048 + t * 8;

  int lane = t & 63, wv = t >> 6;
  int wm = (wv >> 1) * 64, wn = (wv & 1) * 64;
  int lm = lane & 15, kg = lane >> 4;
  int ao[4], bo[4];
#pragma unroll
  for (int i = 0; i < 4; ++i) {
    ao[i] = (wm + i * 16 + lm) * 32 + kg * 8;
    bo[i] = (wn + i * 16 + lm) * 32 + kg * 8;
  }

  f32x4 acc[4][4];
#pragma unroll
  for (int i = 0; i < 4; ++i)
#pragma unroll
    for (int j = 0; j < 4; ++j) acc[i][j] = 0.f;

  gload_lds16(ag0, As[0] + d0);
  gload_lds16(ag1, As[0] + d1);
  gload_lds16(bg0, Bs[0] + d0);
  gload_lds16(bg1, Bs[0] + d1);

  for (int k0 = 0; k0 < IDIM; k0 += 32) {
    int cur = (k0 >> 5) & 1;
    __syncthreads();
    if (k0 + 32 < IDIM) {
      int nx = cur ^ 1, kn = k0 + 32;
      gload_lds16(ag0 + kn, As[nx] + d0);
      gload_lds16(ag1 + kn, As[nx] + d1);
      gload_lds16(bg0 + kn, Bs[nx] + d0);
      gload_lds16(bg1 + kn, Bs[nx] + d1);
    }
    bf16x8 av[4], bv[4];
#pragma unroll
    for (int i = 0; i < 4; ++i) {
      av[i] = *(const bf16x8*)(As[cur] + ao[i]);
      bv[i] = *(const bf16x8*)(Bs[cur] + bo[i]);
    }
#pragma unroll
    for (int mi = 0; mi < 4; ++mi)
#pragma unroll
      for (int ni = 0; ni < 4; ++ni)
        acc[mi][ni] = __builtin_amdgcn_mfma_f32_16x16x32_bf16(av[mi], bv[ni], acc[mi][ni], 0, 0, 0);
  }

#pragma unroll
  for (int mi = 0; mi < 4; ++mi)
#pragma unroll
    for (int rr = 0; rr < 4; ++rr) {
      int orow = wm + mi * 16 + kg * 4 + rr;
      if (orow < cnt) {
        unsigned short* op = O2 + (size_t)(base_slot + orow) * DDIM + n0;
#pragma unroll
        for (int ni = 0; ni < 4; ++ni)
          op[wn + ni * 16 + lm] = f2bf(acc[mi][ni][rr]);
      }
    }
}

// ---------------- combine: out[t] = O2[slot0] + O2[slot1] (bf16 in, fp32 out) ----------------
__global__ void k_combine(const unsigned short* __restrict__ O2, const int* __restrict__ slot_of,
                          float* __restrict__ out) {
  int tk = blockIdx.x, tt = threadIdx.x;
  int s0 = slot_of[2 * tk], s1 = slot_of[2 * tk + 1];
  us4 a = ((const us4*)(O2 + (size_t)s0 * DDIM))[tt];
  us4 b = ((const us4*)(O2 + (size_t)s1 * DDIM))[tt];
  f32x4 o;
#pragma unroll
  for (int j = 0; j < 4; ++j) o[j] = bf2f(a[j]) + bf2f(b[j]);
  ((f32x4*)(out + (size_t)tk * DDIM))[tt] = o;
}

extern "C" void kernel_launch(void* const* d_in, const int* in_sizes, int n_in,
                              void* d_out, int out_size, void* d_ws, size_t ws_size,
                              hipStream_t stream) {
  const float* x  = (const float*)d_in[0];
  const float* Wg = (const float*)d_in[1];
  const float* W1 = (const float*)d_in[2];
  const float* W2 = (const float*)d_in[3];   // dict order: x, Wg, W1, W2, W3
  const float* W3 = (const float*)d_in[4];
  float* out = (float*)d_out;

  char* ws = (char*)d_ws;
  size_t off = 0;
  unsigned short* Xb = (unsigned short*)(ws + off); off += (size_t)NTOK * DDIM * 2;
  unsigned short* H  = (unsigned short*)(ws + off); off += (size_t)NSLOT * IDIM * 2;
  unsigned short* O2 = (unsigned short*)(ws + off); off += (size_t)NSLOT * DDIM * 2;
  unsigned short* W1T = (unsigned short*)(ws + off); off += (size_t)NEXP * NPAD1 * DDIM * 2;
  unsigned short* W3T = (unsigned short*)(ws + off); off += (size_t)NEXP * NPAD1 * DDIM * 2;
  unsigned short* W2T = (unsigned short*)(ws + off); off += (size_t)NEXP * DDIM * IDIM * 2;
  int* counts  = (int*)(ws + off); off += 64;
  int* offsets = (int*)(ws + off); off += 128;
  int* ntiles  = (int*)(ws + off); off += 64;
  int* tile_e  = (int*)(ws + off); off += MAXT * 4;
  int* tile_m0 = (int*)(ws + off); off += MAXT * 4;
  int* tok_e   = (int*)(ws + off); off += NSLOT * 4;
  float* tok_w = (float*)(ws + off); off += NSLOT * 4;
  int* token_map = (int*)(ws + off); off += NSLOT * 4;
  float* gate_w  = (float*)(ws + off); off += NSLOT * 4;
  int* slot_of   = (int*)(ws + off); off += NSLOT * 4;

  k_front<<<RTRBLK + TRBLK, 256, 0, stream>>>(x, Wg, W1, W3, W2, tok_e, tok_w, Xb,
                                              W1T, W3T, W2T);
  k_scan_scatter<<<NEXP, 256, 0, stream>>>(tok_e, tok_w, counts, offsets, ntiles,
                                           tile_e, tile_m0, token_map, gate_w, slot_of);
  k_gemm1<<<480, 256, 0, stream>>>(Xb, W1T, W3T, token_map, gate_w, ntiles, tile_e,
                                   tile_m0, offsets, counts, H);
  k_gemm2<<<640, 256, 0, stream>>>(H, W2T, ntiles, tile_e, tile_m0, offsets, counts, O2);
  k_combine<<<4096, 256, 0, stream>>>(O2, slot_of, out);
}